// Round 4
// baseline (378.118 us; speedup 1.0000x reference)
//
#include <hip/hip_runtime.h>
#include <hip/hip_bf16.h>

// Connected filter:
//   vals[i] = sigmoid(clamp(100*(attrs[i]·w + b), ±12)) * residue[i]
//   cum[i]  = sum of vals along parent chain from i up to root (dummy N terminates)
//   out[p]  = cum[pixel_to_node[p]]
// parent[i] < i (topological), parent[N] = N (dummy, val 0).
//
// Walk in LEVELS (cutoffs 16K/256K/1M/N): nodes in [c_{k-1}, c_k) walk only
// until the chain drops below c_{k-1} (E[hops] = E[ln(i/c)] ≈ 0.85 at ratio 4),
// then add cum of that ancestor. Cuts cold random 64B line-pulls ~2.3x vs the
// 3-level version (R=16 -> E[hops] 1.96).
//
// NOTE: __builtin_nontemporal_* requires native (ext_vector_type) vectors,
// not HIP_vector_type structs.

typedef float v2f __attribute__((ext_vector_type(2)));
typedef float v4f __attribute__((ext_vector_type(4)));
typedef int   v4i __attribute__((ext_vector_type(4)));

// ---------------- Kernel 1: gate + pack (par, val) into 8B records ------------
__global__ void k_gate_pack(const float* __restrict__ attrs,
                            const float* __restrict__ w,
                            const float* __restrict__ bias,
                            const float* __restrict__ residue,
                            const int*   __restrict__ parent,
                            int2* __restrict__ packed,   // .x = par, .y = val bits
                            int N) {
    int i = blockIdx.x * blockDim.x + threadIdx.x;
    if (i > N) return;
    if (i == N) {
        int2 p; p.x = N; p.y = __float_as_int(0.0f);
        packed[N] = p;
        return;
    }
    // row i: 6 floats, 24B stride -> three aligned 8B loads (24*i % 8 == 0)
    const v2f* a2 = reinterpret_cast<const v2f*>(attrs + (size_t)i * 6);
    v2f a0  = __builtin_nontemporal_load(a2 + 0);
    v2f a1  = __builtin_nontemporal_load(a2 + 1);
    v2f a2v = __builtin_nontemporal_load(a2 + 2);
    float logit = bias[0]
                + a0.x  * w[0] + a0.y  * w[1]
                + a1.x  * w[2] + a1.y  * w[3]
                + a2v.x * w[4] + a2v.y * w[5];
    float s = fminf(fmaxf(100.0f * logit, -12.0f), 12.0f);
    float gate = 1.0f / (1.0f + __expf(-s));
    float v = gate * __builtin_nontemporal_load(residue + i);
    int2 p; p.x = __builtin_nontemporal_load(parent + i); p.y = __float_as_int(v);
    packed[i] = p;
}

// ---------------- Kernel 2a: full walk for the base prefix [0, hi) -----------
__global__ void k_walk_lvl0(const int2* __restrict__ packed,
                            float* __restrict__ cum, int hi, int N) {
    int i = blockIdx.x * blockDim.x + threadIdx.x;
    if (i >= hi) return;
    float s = 0.0f;
    int j = i;
    while (j != N) {               // chain stays < hi (parent[i] < i); hot data
        int2 pv = packed[j];
        s += __int_as_float(pv.y);
        j = pv.x;
    }
    cum[i] = s;
}

// ---------------- Kernel 2b: leveled walk for [lo, hi), stop below cutoff ----
__global__ void k_walk_lvl(const int2* __restrict__ packed,
                           float* __restrict__ cum, int lo, int hi, int cutoff) {
    int i = lo + blockIdx.x * blockDim.x + threadIdx.x;
    if (i >= hi) return;
    float s = 0.0f;
    int j = i;
    do {                            // first load is coalesced (j == i == lane-seq)
        int2 pv = packed[j];
        s += __int_as_float(pv.y);
        j = pv.x;
    } while (j >= cutoff);          // parent[j] < j, so this terminates
    cum[i] = s + cum[j];            // ancestor cum already computed (< cutoff)
}

// ---------------- Kernel 3: pixel gather, x8 per thread ----------------------
__global__ void k_pixel_gather(const float* __restrict__ cum,
                               const int* __restrict__ ptn,
                               float* __restrict__ out, int M) {
    int t = blockIdx.x * blockDim.x + threadIdx.x;
    int base = t * 8;
    if (base + 7 < M) {
        const v4i* p4 = reinterpret_cast<const v4i*>(ptn) + t * 2;
        v4i ia = __builtin_nontemporal_load(p4 + 0);
        v4i ib = __builtin_nontemporal_load(p4 + 1);
        v4f oa, ob;                 // 8 independent gathers in flight
        oa.x = cum[ia.x]; oa.y = cum[ia.y]; oa.z = cum[ia.z]; oa.w = cum[ia.w];
        ob.x = cum[ib.x]; ob.y = cum[ib.y]; ob.z = cum[ib.z]; ob.w = cum[ib.w];
        v4f* o4 = reinterpret_cast<v4f*>(out) + t * 2;
        __builtin_nontemporal_store(oa, o4 + 0);
        __builtin_nontemporal_store(ob, o4 + 1);
    } else {
        for (int p = base; p < M; ++p) out[p] = cum[ptn[p]];
    }
}

extern "C" void kernel_launch(void* const* d_in, const int* in_sizes, int n_in,
                              void* d_out, int out_size, void* d_ws, size_t ws_size,
                              hipStream_t stream) {
    const float* attrs   = (const float*)d_in[0];   // (N,6)
    const float* weight  = (const float*)d_in[1];   // (6,)
    const float* bias    = (const float*)d_in[2];   // (1,)
    const float* residue = (const float*)d_in[3];   // (N,)
    const int*   parent  = (const int*)d_in[4];     // (N+1,)
    const int*   ptn     = (const int*)d_in[5];     // (H*W,)
    float* out = (float*)d_out;

    const int N  = in_sizes[3];
    const int HW = in_sizes[5];

    const int BLK = 256;
    const size_t packedBytes = (size_t)(N + 1) * 8;

    int2*  packed = (int2*)d_ws;
    float* cum    = (float*)((char*)d_ws + packedBytes);

    // 1) gate + pack
    int g1 = (N + 1 + BLK - 1) / BLK;
    k_gate_pack<<<g1, BLK, 0, stream>>>(attrs, weight, bias, residue, parent,
                                        packed, N);

    // 2) leveled walk: cutoffs 16K / 256K / 1M / N
    int c0 = 16384;    if (c0 > N) c0 = N;
    int c1 = 262144;   if (c1 > N) c1 = N;
    int c2 = 1048576;  if (c2 > N) c2 = N;

    int g20 = (c0 + BLK - 1) / BLK;
    k_walk_lvl0<<<g20, BLK, 0, stream>>>(packed, cum, c0, N);
    if (c1 > c0) {
        int n1 = c1 - c0;
        k_walk_lvl<<<(n1 + BLK - 1) / BLK, BLK, 0, stream>>>(packed, cum, c0, c1, c0);
    }
    if (c2 > c1) {
        int n2 = c2 - c1;
        k_walk_lvl<<<(n2 + BLK - 1) / BLK, BLK, 0, stream>>>(packed, cum, c1, c2, c1);
    }
    if (N > c2) {
        int n3 = N - c2;
        k_walk_lvl<<<(n3 + BLK - 1) / BLK, BLK, 0, stream>>>(packed, cum, c2, N, c2);
    }

    // 3) pixel gather (x8 per thread)
    int nOct = (HW + 7) / 8;
    int g3 = (nOct + BLK - 1) / BLK;
    k_pixel_gather<<<g3, BLK, 0, stream>>>(cum, ptn, out, HW);
}

// Round 5
// 361.932 us; speedup vs baseline: 1.0447x; 1.0447x over previous
//
#include <hip/hip_runtime.h>
#include <hip/hip_bf16.h>

// Connected filter:
//   vals[i] = sigmoid(clamp(100*(attrs[i]·w + b), ±12)) * residue[i]
//   cum[i]  = sum of vals along parent chain from i up to root (dummy N terminates)
//   out[p]  = cum[pixel_to_node[p]]
// parent[i] < i (topological), parent[N] = N (dummy, val 0).
//
// Walk in LEVELS (cutoffs 16K/256K/1M/N): nodes in [c_{k-1}, c_k) walk only
// until the chain drops below c_{k-1}, then add cum of that ancestor.
//
// Lessons baked in:
//  - __builtin_nontemporal_* needs ext_vector_type, not HIP_vector_type.
//  - nt STORES on gfx950 doubled WRITE_SIZE (65->125MB, +24us) -> plain stores.
//    nt loads for streaming inputs are fine (slight FETCH reduction).

typedef float v2f __attribute__((ext_vector_type(2)));
typedef float v4f __attribute__((ext_vector_type(4)));
typedef int   v4i __attribute__((ext_vector_type(4)));

// ---------------- Kernel 1: gate + pack (par, val) into 8B records ------------
__global__ void k_gate_pack(const float* __restrict__ attrs,
                            const float* __restrict__ w,
                            const float* __restrict__ bias,
                            const float* __restrict__ residue,
                            const int*   __restrict__ parent,
                            int2* __restrict__ packed,   // .x = par, .y = val bits
                            int N) {
    int i = blockIdx.x * blockDim.x + threadIdx.x;
    if (i > N) return;
    if (i == N) {
        int2 p; p.x = N; p.y = __float_as_int(0.0f);
        packed[N] = p;
        return;
    }
    // row i: 6 floats, 24B stride -> three aligned 8B loads (24*i % 8 == 0)
    const v2f* a2 = reinterpret_cast<const v2f*>(attrs + (size_t)i * 6);
    v2f a0  = __builtin_nontemporal_load(a2 + 0);
    v2f a1  = __builtin_nontemporal_load(a2 + 1);
    v2f a2v = __builtin_nontemporal_load(a2 + 2);
    float logit = bias[0]
                + a0.x  * w[0] + a0.y  * w[1]
                + a1.x  * w[2] + a1.y  * w[3]
                + a2v.x * w[4] + a2v.y * w[5];
    float s = fminf(fmaxf(100.0f * logit, -12.0f), 12.0f);
    float gate = 1.0f / (1.0f + __expf(-s));
    float v = gate * __builtin_nontemporal_load(residue + i);
    int2 p; p.x = __builtin_nontemporal_load(parent + i); p.y = __float_as_int(v);
    packed[i] = p;                 // plain store (written then re-read by walk)
}

// ---------------- Kernel 2a: full walk for the base prefix [0, hi) -----------
__global__ void k_walk_lvl0(const int2* __restrict__ packed,
                            float* __restrict__ cum, int hi, int N) {
    int i = blockIdx.x * blockDim.x + threadIdx.x;
    if (i >= hi) return;
    float s = 0.0f;
    int j = i;
    while (j != N) {               // chain stays < hi (parent[i] < i); hot data
        int2 pv = packed[j];
        s += __int_as_float(pv.y);
        j = pv.x;
    }
    cum[i] = s;
}

// ---------------- Kernel 2b: leveled walk for [lo, hi), stop below cutoff ----
__global__ void k_walk_lvl(const int2* __restrict__ packed,
                           float* __restrict__ cum, int lo, int hi, int cutoff) {
    int i = lo + blockIdx.x * blockDim.x + threadIdx.x;
    if (i >= hi) return;
    float s = 0.0f;
    int j = i;
    do {                            // first load is coalesced (j == i == lane-seq)
        int2 pv = packed[j];
        s += __int_as_float(pv.y);
        j = pv.x;
    } while (j >= cutoff);          // parent[j] < j, so this terminates
    cum[i] = s + cum[j];            // ancestor cum already computed (< cutoff)
}

// ---------------- Kernel 3: pixel gather, x8 per thread ----------------------
__global__ void k_pixel_gather(const float* __restrict__ cum,
                               const int* __restrict__ ptn,
                               float* __restrict__ out, int M) {
    int t = blockIdx.x * blockDim.x + threadIdx.x;
    int base = t * 8;
    if (base + 7 < M) {
        const v4i* p4 = reinterpret_cast<const v4i*>(ptn) + t * 2;
        v4i ia = __builtin_nontemporal_load(p4 + 0);
        v4i ib = __builtin_nontemporal_load(p4 + 1);
        float4 oa, ob;              // 8 independent gathers in flight
        oa.x = cum[ia.x]; oa.y = cum[ia.y]; oa.z = cum[ia.z]; oa.w = cum[ia.w];
        ob.x = cum[ib.x]; ob.y = cum[ib.y]; ob.z = cum[ib.z]; ob.w = cum[ib.w];
        float4* o4 = reinterpret_cast<float4*>(out) + t * 2;
        o4[0] = oa;                 // PLAIN stores — nt-store doubled WRITE_SIZE
        o4[1] = ob;
    } else {
        for (int p = base; p < M; ++p) out[p] = cum[ptn[p]];
    }
}

extern "C" void kernel_launch(void* const* d_in, const int* in_sizes, int n_in,
                              void* d_out, int out_size, void* d_ws, size_t ws_size,
                              hipStream_t stream) {
    const float* attrs   = (const float*)d_in[0];   // (N,6)
    const float* weight  = (const float*)d_in[1];   // (6,)
    const float* bias    = (const float*)d_in[2];   // (1,)
    const float* residue = (const float*)d_in[3];   // (N,)
    const int*   parent  = (const int*)d_in[4];     // (N+1,)
    const int*   ptn     = (const int*)d_in[5];     // (H*W,)
    float* out = (float*)d_out;

    const int N  = in_sizes[3];
    const int HW = in_sizes[5];

    const int BLK = 256;
    const size_t packedBytes = (size_t)(N + 1) * 8;

    int2*  packed = (int2*)d_ws;
    float* cum    = (float*)((char*)d_ws + packedBytes);

    // 1) gate + pack
    int g1 = (N + 1 + BLK - 1) / BLK;
    k_gate_pack<<<g1, BLK, 0, stream>>>(attrs, weight, bias, residue, parent,
                                        packed, N);

    // 2) leveled walk: cutoffs 16K / 256K / 1M / N
    int c0 = 16384;    if (c0 > N) c0 = N;
    int c1 = 262144;   if (c1 > N) c1 = N;
    int c2 = 1048576;  if (c2 > N) c2 = N;

    int g20 = (c0 + BLK - 1) / BLK;
    k_walk_lvl0<<<g20, BLK, 0, stream>>>(packed, cum, c0, N);
    if (c1 > c0) {
        int n1 = c1 - c0;
        k_walk_lvl<<<(n1 + BLK - 1) / BLK, BLK, 0, stream>>>(packed, cum, c0, c1, c0);
    }
    if (c2 > c1) {
        int n2 = c2 - c1;
        k_walk_lvl<<<(n2 + BLK - 1) / BLK, BLK, 0, stream>>>(packed, cum, c1, c2, c1);
    }
    if (N > c2) {
        int n3 = N - c2;
        k_walk_lvl<<<(n3 + BLK - 1) / BLK, BLK, 0, stream>>>(packed, cum, c2, N, c2);
    }

    // 3) pixel gather (x8 per thread)
    int nOct = (HW + 7) / 8;
    int g3 = (nOct + BLK - 1) / BLK;
    k_pixel_gather<<<g3, BLK, 0, stream>>>(cum, ptn, out, HW);
}